// Round 1
// baseline (21.084 us; speedup 1.0000x reference)
//
#include <hip/hip_runtime.h>

#define T_ 256
#define B_ 8
#define D_ 256
#define N_ 64
#define NPAIR (T_ * B_)   // 2048
#define CAP 128           // per-bucket capacity (mean 32, +17 sigma safe)
#define JT 8              // vectors per tile (register blocking factor)
#define MAXTILES 320      // >= sum ceil(c_n/8) <= (2048 + 64*7)/8 = 312

// ws int layout:
//   [0]                     ntiles
//   [16 .. 16+64)           counts per position
//   [128 .. 128+64*CAP)     bucket lists (pair indices)
//   [128+64*CAP .. +320)    tile worklist: (n<<16)|start
#define WS_COUNTS 16
#define WS_LISTS  128
#define WS_TILES  (128 + N_ * CAP)

__global__ __launch_bounds__(256) void build_tiles_kernel(
    const void* __restrict__ positions_raw, int* __restrict__ ws) {
  __shared__ int lcnt[N_];
  __shared__ int lofs[N_];
  __shared__ int is64;
  const int t = threadIdx.x;
  if (t < N_) lcnt[t] = 0;
  if (t == 0) {
    // detect int64 vs int32 layout: if int64 (values < 64), every odd
    // 32-bit word is 0. Probability of 32 consecutive zero odd-words in
    // int32 layout ~ (1/64)^32 ~ 0. Reads only first 256B (safe either way).
    const int* p32 = (const int*)positions_raw;
    int nz = 0;
    for (int k = 1; k < 64; k += 2) nz |= p32[k];
    is64 = (nz == 0) ? 1 : 0;
  }
  __syncthreads();
  const int use64 = is64;
  const int* p32 = (const int*)positions_raw;
  const long long* p64 = (const long long*)positions_raw;
  int* lists = ws + WS_LISTS;
  for (int idx = t; idx < NPAIR; idx += blockDim.x) {
    int n = use64 ? (int)p64[idx] : p32[idx];
    int slot = atomicAdd(&lcnt[n], 1);
    if (slot < CAP) lists[n * CAP + slot] = idx;
  }
  __syncthreads();
  if (t == 0) {
    int run = 0;
    for (int n = 0; n < N_; ++n) {
      lofs[n] = run;
      run += (lcnt[n] + JT - 1) / JT;
    }
    ws[0] = run;  // ntiles
  }
  __syncthreads();
  if (t < N_) {
    ws[WS_COUNTS + t] = lcnt[t];
    int ofs = lofs[t];
    int c = lcnt[t];
    int* tiles = ws + WS_TILES;
    for (int k = 0; k * JT < c; ++k) tiles[ofs + k] = (t << 16) | (k * JT);
  }
}

__global__ __launch_bounds__(256) void matvec_tiles_kernel(
    const int* __restrict__ ws, const float* __restrict__ outputs,
    const float* __restrict__ table, float* __restrict__ out) {
  __shared__ float vt[D_][JT];       // 8 KB, transposed vectors
  __shared__ float red[4][JT][D_];   // 32 KB, cross-wave partials
  __shared__ int sidx[JT];

  const int ntiles = ws[0];
  const int b = blockIdx.x;
  // XCD swizzle: 320 = 8*40 exactly -> bijective. Worklist is ordered by
  // position n, so each XCD sees a contiguous run of tiles sharing matrices.
  const int tid = (b & 7) * (MAXTILES / 8) + (b >> 3);
  if (tid >= ntiles) return;

  const int t = threadIdx.x;
  const int packed = ws[WS_TILES + tid];
  const int n = packed >> 16;
  const int start = packed & 0xFFFF;
  const int c = ws[WS_COUNTS + n];
  const int jc = min(JT, c - start);
  const int* list = ws + WS_LISTS + n * CAP + start;
  if (t < JT) sidx[t] = (t < jc) ? list[t] : -1;
  __syncthreads();

  // gather vectors transposed into LDS (coalesced per j)
#pragma unroll
  for (int j = 0; j < JT; ++j) {
    int idx = sidx[j];
    vt[t][j] = (idx >= 0) ? outputs[idx * D_ + t] : 0.0f;
  }
  __syncthreads();

  const int w = t >> 6;   // wave id -> d-range [64w, 64w+64)
  const int l = t & 63;   // lane -> columns 4l..4l+3
  const float4* Mrow = (const float4*)(table + (size_t)n * D_ * D_);

  float4 acc[JT];
#pragma unroll
  for (int j = 0; j < JT; ++j) acc[j] = make_float4(0.f, 0.f, 0.f, 0.f);

  const int d0 = w * 64;
#pragma unroll 4
  for (int dd = 0; dd < 64; ++dd) {
    const int d = d0 + dd;
    float4 m = Mrow[d * 64 + l];                       // coalesced 16B/lane
    const float4* vp = (const float4*)&vt[d][0];       // broadcast reads
    float4 va = vp[0], vb = vp[1];
    float vj[JT] = {va.x, va.y, va.z, va.w, vb.x, vb.y, vb.z, vb.w};
#pragma unroll
    for (int j = 0; j < JT; ++j) {
      acc[j].x += m.x * vj[j];
      acc[j].y += m.y * vj[j];
      acc[j].z += m.z * vj[j];
      acc[j].w += m.w * vj[j];
    }
  }

#pragma unroll
  for (int j = 0; j < JT; ++j) *(float4*)&red[w][j][4 * l] = acc[j];
  __syncthreads();

  // final reduce across the 4 waves (fixed order -> deterministic) + store
#pragma unroll
  for (int j = 0; j < JT; ++j) {
    int idx = sidx[j];
    if (idx >= 0) {
      float s = red[0][j][t] + red[1][j][t] + red[2][j][t] + red[3][j][t];
      out[idx * D_ + t] = s;
    }
  }
}

extern "C" void kernel_launch(void* const* d_in, const int* in_sizes, int n_in,
                              void* d_out, int out_size, void* d_ws,
                              size_t ws_size, hipStream_t stream) {
  const void* positions = d_in[0];
  const float* outputs = (const float*)d_in[1];
  const float* table = (const float*)d_in[2];
  float* out = (float*)d_out;
  int* ws = (int*)d_ws;

  build_tiles_kernel<<<1, 256, 0, stream>>>(positions, ws);
  matvec_tiles_kernel<<<MAXTILES, 256, 0, stream>>>(ws, outputs, table, out);
}